// Round 1
// baseline (289.626 us; speedup 1.0000x reference)
//
#include <hip/hip_runtime.h>

// BertAttention fused: fp32 in/out, bf16 MFMA compute internally.
// cvt(fp32->bf16, + mask*log2e) -> QKV proj (async dbuf GEMM 128x64 tiles,
// XCD swizzle) -> flash attention (S^T/O^T, 4-wave blocks, 16q/wave, dbuf K/V,
// register-resident P via permlane16/32_swap redistribution, no-max bounded
// softmax, deferred l-reduction) -> out proj + residual -> LN.
// B=4 S=2048 DM=768 H=12 HD=64 NSYN=4, scale=1/8, eps=1e-12.

typedef __bf16 bf16;
typedef __bf16 bf16x8 __attribute__((ext_vector_type(8)));
typedef __bf16 bf16x4 __attribute__((ext_vector_type(4)));
typedef float floatx4 __attribute__((ext_vector_type(4)));
typedef unsigned int uint2v __attribute__((ext_vector_type(2)));

#define BB 4
#define SS 2048
#define DM 768
#define HH 12
#define HD 64
#define NSYN 4
#define MM (BB*SS)          // 8192 rows
#define KK DM               // 768
#define SCALE 0.125f
#define LOG2E 1.4426950408889634f

#define N_X   ((size_t)MM * DM)      // 6,291,456
#define N_W   ((size_t)DM * DM)      // 589,824
#define N_M   ((size_t)BB * SS)      // 8,192 (mask)

#if __has_builtin(__builtin_amdgcn_exp2f)
#define EXP2(x) __builtin_amdgcn_exp2f(x)
#else
#define EXP2(x) exp2f(x)
#endif

// async 16B/lane global->LDS copy; lane i of the wave lands at ldsbase + i*16
#define ASYNC16(gp, lp)                                                        \
    __builtin_amdgcn_global_load_lds(                                          \
        (const __attribute__((address_space(1))) unsigned int*)(gp),           \
        (__attribute__((address_space(3))) unsigned int*)(lp), 16, 0, 0)

// gfx950 dual-register half-swaps (VALU, full-rate).
// pl32: new_a[32:63] = old_b[0:31], new_b[0:31] = old_a[32:63] (rest kept).
// pl16: within each 32-group: new_a[16:31] = old_b[0:15],
//       new_b[0:15] = old_a[16:31] (rest kept).
static __device__ __forceinline__ void pl32_swap(unsigned int& a, unsigned int& b) {
#if __has_builtin(__builtin_amdgcn_permlane32_swap)
    uint2v r = __builtin_amdgcn_permlane32_swap(a, b, false, false);
    a = r[0]; b = r[1];
#else
    asm volatile("v_permlane32_swap_b32 %0, %1" : "+v"(a), "+v"(b));
#endif
}
static __device__ __forceinline__ void pl16_swap(unsigned int& a, unsigned int& b) {
#if __has_builtin(__builtin_amdgcn_permlane16_swap)
    uint2v r = __builtin_amdgcn_permlane16_swap(a, b, false, false);
    a = r[0]; b = r[1];
#else
    asm volatile("v_permlane16_swap_b32 %0, %1" : "+v"(a), "+v"(b));
#endif
}

// ---------------------------------------------------------------------------
// Kernel 0: fp32 -> bf16 for x and 4 weights; mask -> mask*LOG2E (fp32).
// ---------------------------------------------------------------------------
__global__ __launch_bounds__(256) void cvt_kernel(
    const float* __restrict__ x,
    const float* __restrict__ Wq, const float* __restrict__ Wk,
    const float* __restrict__ Wv, const float* __restrict__ Wo,
    const float* __restrict__ mask,
    bf16* __restrict__ xb,
    bf16* __restrict__ Wqb, bf16* __restrict__ Wkb,
    bf16* __restrict__ Wvb, bf16* __restrict__ Wob,
    float* __restrict__ ml2e)
{
    const size_t nx4 = N_X / 4, nw4 = N_W / 4, nm4 = N_M / 4;
    size_t i = (size_t)blockIdx.x * blockDim.x + threadIdx.x;
    if (i >= nx4 + 4 * nw4) {
        size_t off = i - nx4 - 4 * nw4;
        if (off < nm4) {
            float4 m = *(const float4*)(mask + off * 4);
            float4 o = { m.x * LOG2E, m.y * LOG2E, m.z * LOG2E, m.w * LOG2E };
            *(float4*)(ml2e + off * 4) = o;
        }
        return;
    }
    const float* src; bf16* dst; size_t off;
    if (i < nx4)                { src = x;  dst = xb;  off = i; }
    else if (i < nx4 + nw4)     { src = Wq; dst = Wqb; off = i - nx4; }
    else if (i < nx4 + 2*nw4)   { src = Wk; dst = Wkb; off = i - nx4 - nw4; }
    else if (i < nx4 + 3*nw4)   { src = Wv; dst = Wvb; off = i - nx4 - 2*nw4; }
    else                        { src = Wo; dst = Wob; off = i - nx4 - 3*nw4; }
    float4 v = *(const float4*)(src + off * 4);
    bf16x4 o = { (bf16)v.x, (bf16)v.y, (bf16)v.z, (bf16)v.w };
    *(bf16x4*)(dst + off * 4) = o;
}

// ---------------------------------------------------------------------------
// GEMM mainloop, 128(M) x 64(N) tile = A[M,K] · Bw[N,K]^T, double-buffered
// async staging, XOR chunk swizzle.  4 waves; wave w owns M rows
// [w*32, w*32+32) x all 64 N.  acc[2][4].
// ORD=0: D[m=A-row(quad*4+r)][n=B-row(l15)];
// ORD=1: swapped -> D[m=B-row(quad*4+r)][n=A-row(l15)].
// ---------------------------------------------------------------------------
template<int ORD>
__device__ __forceinline__ void gemm_mainloop64(
    const bf16* __restrict__ A, const bf16* __restrict__ Bw,
    int tileM, int tileN, bf16* As, bf16* Bs, floatx4 acc[2][4])
{
    const int tid  = threadIdx.x;
    const int lane = tid & 63;
    const int wave = tid >> 6;
    const int l15 = lane & 15, quad = lane >> 4;

    const int r0a = wave * 32 + (lane >> 2);
    const int r0b = wave * 16 + (lane >> 2);
    const int cl  = (lane & 3) ^ ((lane >> 2) & 3);   // swizzled chunk (r0&3)
    const bf16* gA = A  + (size_t)(tileM * 128 + r0a) * KK + cl * 8;
    const bf16* gB = Bw + (size_t)(tileN *  64 + r0b) * KK + cl * 8;
    bf16* lA = As + (wave * 32) * 32;   // + lane*16B implicit (HW)
    bf16* lB = Bs + (wave * 16) * 32;

    ASYNC16(gA,           lA);
    ASYNC16(gA + 16 * KK, lA + 16 * 32);
    ASYNC16(gB,           lB);
    __syncthreads();

    const int fpc = quad ^ (l15 & 3);   // fragment physical chunk
    for (int kt = 0; kt < KK / 32; ++kt) {
        const int cur = kt & 1;
        if (kt + 1 < KK / 32) {
            const int nbA = (1 - cur) * 4096;    // elems (128*32)
            const int nbB = (1 - cur) * 2048;    // elems (64*32)
            ASYNC16(gA + (kt + 1) * 32,           lA + nbA);
            ASYNC16(gA + (kt + 1) * 32 + 16 * KK, lA + nbA + 16 * 32);
            ASYNC16(gB + (kt + 1) * 32,           lB + nbB);
        }
        const bf16* cA = As + cur * 4096;
        const bf16* cB = Bs + cur * 2048;
        bf16x8 af[2], bfr[4];
        #pragma unroll
        for (int i = 0; i < 2; ++i)
            af[i] = *(const bf16x8*)(cA + (wave * 32 + i * 16 + l15) * 32 + fpc * 8);
        #pragma unroll
        for (int j = 0; j < 4; ++j)
            bfr[j] = *(const bf16x8*)(cB + (j * 16 + l15) * 32 + fpc * 8);
        #pragma unroll
        for (int i = 0; i < 2; ++i)
            #pragma unroll
            for (int j = 0; j < 4; ++j)
                acc[i][j] = (ORD == 0)
                    ? __builtin_amdgcn_mfma_f32_16x16x32_bf16(af[i], bfr[j], acc[i][j], 0, 0, 0)
                    : __builtin_amdgcn_mfma_f32_16x16x32_bf16(bfr[j], af[i], acc[i][j], 0, 0, 0);
        __syncthreads();
    }
}

// ---------------------------------------------------------------------------
// Kernel 1: QKV projection.  1-D grid of 2304 (64 tileM x 12 tileN x 3 z),
// XCD swizzle: tileM = u % 64 (36 sharers of an x-tile are 64-strided).
// z=0/1 use ORD=1 (pack 4 consecutive d per lane); z=2 ORD=0 (V^T store).
// ---------------------------------------------------------------------------
__global__ __launch_bounds__(256) void qkv_kernel(
    const bf16* __restrict__ xb,
    const bf16* __restrict__ Wqb, const float* __restrict__ bq,
    const bf16* __restrict__ Wkb, const float* __restrict__ bk,
    const bf16* __restrict__ Wvb, const float* __restrict__ bv,
    const float* __restrict__ addi_key, const float* __restrict__ addi_value,
    bf16* __restrict__ qbuf, bf16* __restrict__ kbuf, bf16* __restrict__ vtbuf)
{
    __shared__ __align__(16) bf16 As[2 * 128 * 32];
    __shared__ __align__(16) bf16 Bs[2 * 64 * 32];
    const int u = blockIdx.x;
    const int tileM = u & 63;
    const int r     = u >> 6;            // 0..35
    const int tileN = r % 12;
    const int z     = r / 12;            // 0..2
    const bf16* W     = (z == 0) ? Wqb : (z == 1) ? Wkb : Wvb;
    const float* bias = (z == 0) ? bq  : (z == 1) ? bk  : bv;

    floatx4 acc[2][4];
    #pragma unroll
    for (int i = 0; i < 2; ++i)
        #pragma unroll
        for (int j = 0; j < 4; ++j) { floatx4 zv = {0.f, 0.f, 0.f, 0.f}; acc[i][j] = zv; }

    const int lane = threadIdx.x & 63, wave = threadIdx.x >> 6;
    const int l15 = lane & 15, quad = lane >> 4;

    if (z == 2) {
        gemm_mainloop64<0>(xb, W, tileM, tileN, As, Bs, acc);
        // D: m = x-row sg (chunks quad*4+r), n = W-row o (l15)
        #pragma unroll
        for (int i = 0; i < 2; ++i) {
            const int sg0 = tileM * 128 + wave * 32 + i * 16 + quad * 4;
            const int b = sg0 >> 11, s0 = sg0 & 2047;
            #pragma unroll
            for (int j = 0; j < 4; ++j) {
                const int o = tileN * 64 + j * 16 + l15;
                const float bv_ = bias[o];
                const int h = o >> 6, d = o & 63;
                float vv[4];
                #pragma unroll
                for (int rr = 0; rr < 4; ++rr) {
                    vv[rr] = acc[i][j][rr] + bv_;
                    if (h < NSYN)
                        vv[rr] += addi_value[(((size_t)b * NSYN + h) * SS + s0 + rr) * HD + d];
                }
                bf16x4 pk = { (bf16)vv[0], (bf16)vv[1], (bf16)vv[2], (bf16)vv[3] };
                *(bf16x4*)(vtbuf + (((size_t)b * HH + h) * HD + d) * SS + s0) = pk;
            }
        }
    } else {
        gemm_mainloop64<1>(xb, W, tileM, tileN, As, Bs, acc);
        // D: m = W-row o (chunks quad*4+r), n = x-row sg (l15)
        #pragma unroll
        for (int i = 0; i < 2; ++i) {
            const int sg = tileM * 128 + wave * 32 + i * 16 + l15;
            const int b = sg >> 11, s = sg & 2047;
            #pragma unroll
            for (int j = 0; j < 4; ++j) {
                const int o0 = tileN * 64 + j * 16 + quad * 4;
                const int h = o0 >> 6, d0 = o0 & 63;
                float4 b4 = *(const float4*)(bias + o0);
                float vv[4] = { acc[i][j][0] + b4.x, acc[i][j][1] + b4.y,
                                acc[i][j][2] + b4.z, acc[i][j][3] + b4.w };
                if (z == 1 && h < NSYN) {
                    float4 a4 = *(const float4*)(addi_key +
                        (((size_t)b * NSYN + h) * SS + s) * HD + d0);
                    vv[0] += a4.x; vv[1] += a4.y; vv[2] += a4.z; vv[3] += a4.w;
                }
                if (z == 0) {
                    bf16x4 pk = { (bf16)(vv[0] * SCALE), (bf16)(vv[1] * SCALE),
                                  (bf16)(vv[2] * SCALE), (bf16)(vv[3] * SCALE) };
                    *(bf16x4*)(qbuf + (((size_t)b * HH + h) * SS + s) * HD + d0) = pk;
                } else {
                    bf16x4 pk = { (bf16)vv[0], (bf16)vv[1], (bf16)vv[2], (bf16)vv[3] };
                    *(bf16x4*)(kbuf + (((size_t)b * HH + h) * SS + s) * HD + d0) = pk;
                }
            }
        }
    }
}

// ---------------------------------------------------------------------------
// Kernel 2: flash attention, S^T/O^T, 4-wave blocks (256 thr), 16 q/wave,
// DOUBLE-BUFFERED K/V tiles, register-resident P (no Ps LDS): the S^T
// fragment (lane holds S[q=l15][key=j*16+quad*4+r]) is redistributed to the
// PV B-operand layout (P[q=l15][key=c*32+quad*8+e]) with 4x permlane32_swap
// (route on key-bit b2 across lane^32) + 4x permlane16_swap (route on key-bit
// b1 across lane^16).  LDS = 32KB -> 5 blocks/CU; grid 1536 = 48 bh x 32 qt,
// XCD swizzle bh = u % 48 (all qt of a bh land on one XCD: 48 % 8 == 0).
// No-max bounded softmax, deferred l-reduction.
// ---------------------------------------------------------------------------
__global__ __launch_bounds__(256, 5) void attn_kernel(
    const bf16* __restrict__ qbuf, const bf16* __restrict__ kbuf,
    const bf16* __restrict__ vtbuf, const float* __restrict__ ml2e,
    bf16* __restrict__ ctx)
{
    __shared__ __align__(16) bf16 Ks[2 * 64 * 64];
    __shared__ __align__(16) bf16 Vt[2 * 64 * 64];

    const int u  = blockIdx.x;
    const int bh = u % 48;              // b*12 + h
    const int qt = u / 48;              // 0..31
    const int b  = bh / 12;
    const int h  = bh % 12;
    const size_t bhs = ((size_t)b * HH + h) * SS * HD;  // same for vtbuf (HD*SS)
    const int tid = threadIdx.x, lane = tid & 63, wave = tid >> 6;  // 0..3
    const int l15 = lane & 15, quad = lane >> 4;
    const int q0 = qt * 64 + wave * 16;

    // staging: wave w stages K rows [w*16,w*16+16) and V^T rows likewise,
    // 2 insts each of 8 rows; phys chunk lane&7, swizzle ^ (row&7).
    const int sr  = wave * 16 + (lane >> 3);
    const int scl = (lane & 7) ^ ((lane >> 3) & 7);
    const bf16* gK = kbuf  + bhs + (size_t)sr * HD + scl * 8;
    const bf16* gV = vtbuf + bhs + (size_t)sr * SS + scl * 8;
    bf16* lK = Ks + (wave * 16) * 64;   // + lane*16B implicit
    bf16* lV = Vt + (wave * 16) * 64;

    // Q fragments (B operand: n = q = l15): 2 k-chunks
    bf16x8 qf[2];
    #pragma unroll
    for (int c = 0; c < 2; ++c)
        qf[c] = *(const bf16x8*)(qbuf + bhs +
            (size_t)(q0 + l15) * HD + c * 32 + quad * 8);

    floatx4 acco[4];   // O^T: acco[t][r] = O[q=l15][d=t*16+quad*4+r]
    #pragma unroll
    for (int t = 0; t < 4; ++t) { floatx4 zv = {0.f, 0.f, 0.f, 0.f}; acco[t] = zv; }
    float lrun = 0.f;                   // per-lane partial; reduced after loop

    const float* mb = ml2e + (size_t)b * SS;

    // prefetch kt=0 into buffer 0
    #pragma unroll
    for (int p = 0; p < 2; ++p) {
        ASYNC16(gK + (size_t)p * 8 * HD,  lK + p * 512);
        ASYNC16(gV + (size_t)p * 8 * SS,  lV + p * 512);
    }
    __syncthreads();

    for (int kt = 0; kt < SS / 64; ++kt) {
        const int cur = kt & 1;
        if (kt + 1 < SS / 64) {
            const int nb = (1 - cur) * 4096;    // elems (64*64)
            #pragma unroll
            for (int p = 0; p < 2; ++p) {
                ASYNC16(gK + ((size_t)(kt + 1) * 64 + p * 8) * HD, lK + nb + p * 512);
                ASYNC16(gV + (size_t)p * 8 * SS + (kt + 1) * 64,   lV + nb + p * 512);
            }
        }
        const bf16* cK = Ks + cur * 4096;
        const bf16* cV = Vt + cur * 4096;

        // S^T = K·Q^T : sacc[j][r] = S[q=l15][key=j*16+quad*4+r]
        floatx4 sacc[4];
        #pragma unroll
        for (int j = 0; j < 4; ++j) { floatx4 zv = {0.f, 0.f, 0.f, 0.f}; sacc[j] = zv; }
        #pragma unroll
        for (int c = 0; c < 2; ++c) {
            const int pc = (4 * c + quad) ^ (l15 & 7);
            #pragma unroll
            for (int j = 0; j < 4; ++j) {
                bf16x8 af = *(const bf16x8*)(cK + (j * 16 + l15) * 64 + pc * 8);
                sacc[j] = __builtin_amdgcn_mfma_f32_16x16x32_bf16(af, qf[c], sacc[j], 0, 0, 0);
            }
        }

        // p = exp2(s*log2e + mask*log2e); accumulate per-lane l; pack to u32.
        // Word (key-block B=key/4 bits b3b2b1b0, half h): src register
        // w[j=2*b3+b2][h] at lane quad=(b1,b0).
        unsigned int w[4][2];
        #pragma unroll
        for (int j = 0; j < 4; ++j) {
            float4 mk = *(const float4*)(mb + kt * 64 + j * 16 + quad * 4);
            float p0 = EXP2(__builtin_fmaf(sacc[j][0], LOG2E, mk.x));
            float p1 = EXP2(__builtin_fmaf(sacc[j][1], LOG2E, mk.y));
            float p2 = EXP2(__builtin_fmaf(sacc[j][2], LOG2E, mk.z));
            float p3 = EXP2(__builtin_fmaf(sacc[j][3], LOG2E, mk.w));
            lrun += (p0 + p1) + (p2 + p3);
            union { bf16x4 v; unsigned int u2[2]; } pk;
            pk.v = (bf16x4){ (bf16)p0, (bf16)p1, (bf16)p2, (bf16)p3 };
            w[j][0] = pk.u2[0];
            w[j][1] = pk.u2[1];
        }
        // round 1: route on b2 across lane^32 (pairs j&1 within each b3)
        pl32_swap(w[0][0], w[1][0]);  pl32_swap(w[0][1], w[1][1]);
        pl32_swap(w[2][0], w[3][0]);  pl32_swap(w[2][1], w[3][1]);
        // now w[2*b3 + b1][h] holds (b2 = quad>>1 implicit)
        // round 2: route on b1 across lane^16
        pl16_swap(w[0][0], w[1][0]);  pl16_swap(w[0][1], w[1][1]);
        pl16_swap(w[2][0], w[3][0]);  pl16_swap(w[2][1], w[3][1]);
        // now w[2*c + b0][h] = P[q=l15][key = c*32 + quad*8 + 4*b0 + 2*h +{0,1}]
        union { unsigned int u2[4]; bf16x8 v; } pb[2];
        pb[0].u2[0] = w[0][0]; pb[0].u2[1] = w[0][1];
        pb[0].u2[2] = w[1][0]; pb[0].u2[3] = w[1][1];
        pb[1].u2[0] = w[2][0]; pb[1].u2[1] = w[2][1];
        pb[1].u2[2] = w[3][0]; pb[1].u2[3] = w[3][1];

        // O^T += V^T·P^T  (P fragment straight from registers)
        #pragma unroll
        for (int c = 0; c < 2; ++c) {
            const int pc = (4 * c + quad) ^ (l15 & 7);
            #pragma unroll
            for (int t = 0; t < 4; ++t) {
                bf16x8 af = *(const bf16x8*)(cV + (t * 16 + l15) * 64 + pc * 8);
                acco[t] = __builtin_amdgcn_mfma_f32_16x16x32_bf16(af, pb[c].v, acco[t], 0, 0, 0);
            }
        }
        __syncthreads();   // drain prefetch (after compute) + free cur buffer
    }

    // deferred cross-quad l reduction (sum over keys commutes)
    lrun += __shfl_xor(lrun, 16);
    lrun += __shfl_xor(lrun, 32);
    const float inv = 1.0f / lrun;

    // ctx[B,S,DM]: row q = q0 + l15, col = h*64 + t*16 + quad*4 (x4)
    bf16* crow = ctx + ((size_t)(b * SS + q0 + l15)) * DM + h * HD;
    #pragma unroll
    for (int t = 0; t < 4; ++t) {
        bf16x4 ov = { (bf16)(acco[t][0] * inv), (bf16)(acco[t][1] * inv),
                      (bf16)(acco[t][2] * inv), (bf16)(acco[t][3] * inv) };
        *(bf16x4*)(crow + t * 16 + quad * 4) = ov;
    }
}

// ---------------------------------------------------------------------------
// Kernel 3: output projection + bias + residual x(fp32) -> h (bf16).
// 1-D grid of 768 (64 tileM x 12 tileN), XCD swizzle tileM = u % 64.
// ---------------------------------------------------------------------------
__global__ __launch_bounds__(256) void oproj_kernel(
    const bf16* __restrict__ ctx, const bf16* __restrict__ Wob,
    const float* __restrict__ bo, const float* __restrict__ x,
    bf16* __restrict__ hbuf)
{
    __shared__ __align__(16) bf16 As[2 * 128 * 32];
    __shared__ __align__(16) bf16 Bs[2 * 64 * 32];
    const int u = blockIdx.x;
    const int tileM = u & 63;
    const int tileN = u >> 6;           // 0..11

    floatx4 acc[2][4];
    #pragma unroll
    for (int i = 0; i < 2; ++i)
        #pragma unroll
        for (int j = 0; j < 4; ++j) { floatx4 zv = {0.f, 0.f, 0.f, 0.f}; acc[i][j] = zv; }

    gemm_mainloop64<1>(ctx, Wob, tileM, tileN, As, Bs, acc);

    const int lane = threadIdx.x & 63, wave = threadIdx.x >> 6;
    const int l15 = lane & 15, quad = lane >> 4;
    #pragma unroll
    for (int i = 0; i < 2; ++i) {
        const int sg = tileM * 128 + wave * 32 + i * 16 + l15;
        #pragma unroll
        for (int j = 0; j < 4; ++j) {
            const int o0 = tileN * 64 + j * 16 + quad * 4;
            float4 b4 = *(const float4*)(bo + o0);
            float4 r4 = *(const float4*)(x + (size_t)sg * DM + o0);
            bf16x4 pk = { (bf16)(acc[i][j][0] + b4.x + r4.x),
                          (bf16)(acc[i][j][1] + b4.y + r4.y),
                          (bf16)(acc[i][j][2] + b4.z + r4.z),
                          (bf16)(acc[i][j][3] + b4.w + r4.w) };
            *(bf16x4*)(hbuf + (size_t)sg * DM + o0) = pk;
        }
    }
}

// ---------------------------------------------------------------------------
// Kernel 4: LayerNorm, one wave per row (768 elems = 12/lane), eps=1e-12.
// ---------------------------------------------------------------------------
__global__ __launch_bounds__(256) void ln_kernel(
    const bf16* __restrict__ hbuf, const float* __restrict__ g,
    const float* __restrict__ be, float* __restrict__ out)
{
    const int row  = blockIdx.x * 4 + (threadIdx.x >> 6);
    const int lane = threadIdx.x & 63;
    const bf16* hr = hbuf + (size_t)row * DM;

    bf16x8 va = *(const bf16x8*)(hr + lane * 8);          // elems [0,512)
    bf16x4 vb = *(const bf16x4*)(hr + 512 + lane * 4);    // elems [512,768)
    float v[12];
    #pragma unroll
    for (int i = 0; i < 8; ++i) v[i] = (float)va[i];
    #pragma unroll
    for (int i = 0; i < 4; ++i) v[8 + i] = (float)vb[i];

    float s = 0.f;
    #pragma unroll
    for (int i = 0; i < 12; ++i) s += v[i];
    #pragma unroll
    for (int m = 1; m < 64; m <<= 1) s += __shfl_xor(s, m);
    const float mu = s * (1.0f / DM);

    float s2 = 0.f;
    #pragma unroll
    for (int i = 0; i < 12; ++i) { v[i] -= mu; s2 += v[i] * v[i]; }
    #pragma unroll
    for (int m = 1; m < 64; m <<= 1) s2 += __shfl_xor(s2, m);
    const float rsv = rsqrtf(s2 * (1.0f / DM) + 1e-12f);

    float* orow = out + (size_t)row * DM;
    const int c0 = lane * 8, c1 = 512 + lane * 4;
    float4 g0 = *(const float4*)(g + c0),     g1 = *(const float4*)(g + c0 + 4);
    float4 g2 = *(const float4*)(g + c1);
    float4 b0 = *(const float4*)(be + c0),    b1 = *(const float4*)(be + c0 + 4);
    float4 b2 = *(const float4*)(be + c1);
    float4 o0 = { v[0]*rsv*g0.x + b0.x, v[1]*rsv*g0.y + b0.y,
                  v[2]*rsv*g0.z + b0.z, v[3]*rsv*g0.w + b0.w };
    float4 o1 = { v[4]*rsv*g1.x + b1.x, v[5]*rsv*g1.y + b1.y,
                  v[6]*rsv*g1.z + b1.z, v[7]*rsv*g1.w + b1.w };
    float4 o2 = { v[8]*rsv*g2.x + b2.x, v[9]*rsv*g2.y + b2.y,
                  v[10]*rsv*g2.z + b2.z, v[11]*rsv*g2.w + b2.w };
    *(float4*)(orow + c0)     = o0;
    *(float4*)(orow + c0 + 4) = o1;
    *(float4*)(orow + c1)     = o2;
}

// ---------------------------------------------------------------------------
extern "C" void kernel_launch(void* const* d_in, const int* in_sizes, int n_in,
                              void* d_out, int out_size, void* d_ws, size_t ws_size,
                              hipStream_t stream)
{
    const float* x    = (const float*)d_in[0];
    const float* mask = (const float*)d_in[1];
    const float* akey = (const float*)d_in[2];
    const float* aval = (const float*)d_in[3];
    const float* Wq = (const float*)d_in[4];  const float* bq = (const float*)d_in[5];
    const float* Wk = (const float*)d_in[6];  const float* bk = (const float*)d_in[7];
    const float* Wv = (const float*)d_in[8];  const float* bv = (const float*)d_in[9];
    const float* Wo = (const float*)d_in[10]; const float* bo = (const float*)d_in[11];
    const float* lng = (const float*)d_in[12]; const float* lnb = (const float*)d_in[13];
    float* outp = (float*)d_out;

    const size_t nqkv = (size_t)BB * HH * SS * HD;   // 6,291,456 elems
    char* ws = (char*)d_ws;
    bf16*  xb   = (bf16*)ws;   ws += N_X  * sizeof(bf16);
    bf16*  Wqb  = (bf16*)ws;   ws += N_W  * sizeof(bf16);
    bf16*  Wkb  = (bf16*)ws;   ws += N_W  * sizeof(bf16);
    bf16*  Wvb  = (bf16*)ws;   ws += N_W  * sizeof(bf16);
    bf16*  Wob  = (bf16*)ws;   ws += N_W  * sizeof(bf16);
    float* ml2e = (float*)ws;  ws += N_M  * sizeof(float);
    bf16*  qbuf = (bf16*)ws;   ws += nqkv * sizeof(bf16);
    bf16*  kbuf = (bf16*)ws;   ws += nqkv * sizeof(bf16);
    bf16*  vtbuf= (bf16*)ws;   ws += nqkv * sizeof(bf16);
    bf16*  ctxb = (bf16*)ws;   ws += nqkv * sizeof(bf16);
    bf16*  hbuf = (bf16*)ws;   ws += nqkv * sizeof(bf16);
    // total ~80 MB of d_ws

    const size_t ncvt = (N_X + 4 * N_W + N_M) / 4;       // threads, 4 elems each
    const int cvt_blocks = (int)((ncvt + 255) / 256);
    cvt_kernel<<<cvt_blocks, 256, 0, stream>>>(x, Wq, Wk, Wv, Wo, mask,
                                               xb, Wqb, Wkb, Wvb, Wob, ml2e);

    qkv_kernel<<<2304, 256, 0, stream>>>(xb, Wqb, bq, Wkb, bk, Wvb, bv, akey, aval,
                                         qbuf, kbuf, vtbuf);
    attn_kernel<<<1536, 256, 0, stream>>>(qbuf, kbuf, vtbuf, ml2e, ctxb);
    oproj_kernel<<<768, 256, 0, stream>>>(ctxb, Wob, bo, x, hbuf);
    ln_kernel<<<MM / 4, 256, 0, stream>>>(hbuf, lng, lnb, outp);
}

// Round 2
// 273.713 us; speedup vs baseline: 1.0581x; 1.0581x over previous
//
#include <hip/hip_runtime.h>

// BertAttention fused: fp32 in/out, bf16 MFMA compute internally.
// cvt(fp32->bf16, + mask*log2e) -> QKV proj (async dbuf GEMM 128x64 tiles,
// XCD swizzle) -> flash attention (S^T/O^T, 4-wave blocks, 32q/wave, dbuf K/V,
// register-resident P via permlane16/32_swap redistribution, s_setprio around
// MFMA clusters, no-max bounded softmax, deferred l-reduction)
// -> out proj + residual -> LN.
// B=4 S=2048 DM=768 H=12 HD=64 NSYN=4, scale=1/8, eps=1e-12.

typedef __bf16 bf16;
typedef __bf16 bf16x8 __attribute__((ext_vector_type(8)));
typedef __bf16 bf16x4 __attribute__((ext_vector_type(4)));
typedef float floatx4 __attribute__((ext_vector_type(4)));
typedef unsigned int uint2v __attribute__((ext_vector_type(2)));

#define BB 4
#define SS 2048
#define DM 768
#define HH 12
#define HD 64
#define NSYN 4
#define MM (BB*SS)          // 8192 rows
#define KK DM               // 768
#define SCALE 0.125f
#define LOG2E 1.4426950408889634f

#define N_X   ((size_t)MM * DM)      // 6,291,456
#define N_W   ((size_t)DM * DM)      // 589,824
#define N_M   ((size_t)BB * SS)      // 8,192 (mask)

#if __has_builtin(__builtin_amdgcn_exp2f)
#define EXP2(x) __builtin_amdgcn_exp2f(x)
#else
#define EXP2(x) exp2f(x)
#endif

// async 16B/lane global->LDS copy; lane i of the wave lands at ldsbase + i*16
#define ASYNC16(gp, lp)                                                        \
    __builtin_amdgcn_global_load_lds(                                          \
        (const __attribute__((address_space(1))) unsigned int*)(gp),           \
        (__attribute__((address_space(3))) unsigned int*)(lp), 16, 0, 0)

// gfx950 dual-register half-swaps (VALU, full-rate).
// pl32: new_a[32:63] = old_b[0:31], new_b[0:31] = old_a[32:63] (rest kept).
// pl16: within each 32-group: new_a[16:31] = old_b[0:15],
//       new_b[0:15] = old_a[16:31] (rest kept).
static __device__ __forceinline__ void pl32_swap(unsigned int& a, unsigned int& b) {
#if __has_builtin(__builtin_amdgcn_permlane32_swap)
    uint2v r = __builtin_amdgcn_permlane32_swap(a, b, false, false);
    a = r[0]; b = r[1];
#else
    asm volatile("v_permlane32_swap_b32 %0, %1" : "+v"(a), "+v"(b));
#endif
}
static __device__ __forceinline__ void pl16_swap(unsigned int& a, unsigned int& b) {
#if __has_builtin(__builtin_amdgcn_permlane16_swap)
    uint2v r = __builtin_amdgcn_permlane16_swap(a, b, false, false);
    a = r[0]; b = r[1];
#else
    asm volatile("v_permlane16_swap_b32 %0, %1" : "+v"(a), "+v"(b));
#endif
}

// ---------------------------------------------------------------------------
// Kernel 0: fp32 -> bf16 for x and 4 weights; mask -> mask*LOG2E (fp32).
// ---------------------------------------------------------------------------
__global__ __launch_bounds__(256) void cvt_kernel(
    const float* __restrict__ x,
    const float* __restrict__ Wq, const float* __restrict__ Wk,
    const float* __restrict__ Wv, const float* __restrict__ Wo,
    const float* __restrict__ mask,
    bf16* __restrict__ xb,
    bf16* __restrict__ Wqb, bf16* __restrict__ Wkb,
    bf16* __restrict__ Wvb, bf16* __restrict__ Wob,
    float* __restrict__ ml2e)
{
    const size_t nx4 = N_X / 4, nw4 = N_W / 4, nm4 = N_M / 4;
    size_t i = (size_t)blockIdx.x * blockDim.x + threadIdx.x;
    if (i >= nx4 + 4 * nw4) {
        size_t off = i - nx4 - 4 * nw4;
        if (off < nm4) {
            float4 m = *(const float4*)(mask + off * 4);
            float4 o = { m.x * LOG2E, m.y * LOG2E, m.z * LOG2E, m.w * LOG2E };
            *(float4*)(ml2e + off * 4) = o;
        }
        return;
    }
    const float* src; bf16* dst; size_t off;
    if (i < nx4)                { src = x;  dst = xb;  off = i; }
    else if (i < nx4 + nw4)     { src = Wq; dst = Wqb; off = i - nx4; }
    else if (i < nx4 + 2*nw4)   { src = Wk; dst = Wkb; off = i - nx4 - nw4; }
    else if (i < nx4 + 3*nw4)   { src = Wv; dst = Wvb; off = i - nx4 - 2*nw4; }
    else                        { src = Wo; dst = Wob; off = i - nx4 - 3*nw4; }
    float4 v = *(const float4*)(src + off * 4);
    bf16x4 o = { (bf16)v.x, (bf16)v.y, (bf16)v.z, (bf16)v.w };
    *(bf16x4*)(dst + off * 4) = o;
}

// ---------------------------------------------------------------------------
// GEMM mainloop, 128(M) x 64(N) tile = A[M,K] · Bw[N,K]^T, double-buffered
// async staging, XOR chunk swizzle.  4 waves; wave w owns M rows
// [w*32, w*32+32) x all 64 N.  acc[2][4].
// ORD=0: D[m=A-row(quad*4+r)][n=B-row(l15)];
// ORD=1: swapped -> D[m=B-row(quad*4+r)][n=A-row(l15)].
// ---------------------------------------------------------------------------
template<int ORD>
__device__ __forceinline__ void gemm_mainloop64(
    const bf16* __restrict__ A, const bf16* __restrict__ Bw,
    int tileM, int tileN, bf16* As, bf16* Bs, floatx4 acc[2][4])
{
    const int tid  = threadIdx.x;
    const int lane = tid & 63;
    const int wave = tid >> 6;
    const int l15 = lane & 15, quad = lane >> 4;

    const int r0a = wave * 32 + (lane >> 2);
    const int r0b = wave * 16 + (lane >> 2);
    const int cl  = (lane & 3) ^ ((lane >> 2) & 3);   // swizzled chunk (r0&3)
    const bf16* gA = A  + (size_t)(tileM * 128 + r0a) * KK + cl * 8;
    const bf16* gB = Bw + (size_t)(tileN *  64 + r0b) * KK + cl * 8;
    bf16* lA = As + (wave * 32) * 32;   // + lane*16B implicit (HW)
    bf16* lB = Bs + (wave * 16) * 32;

    ASYNC16(gA,           lA);
    ASYNC16(gA + 16 * KK, lA + 16 * 32);
    ASYNC16(gB,           lB);
    __syncthreads();

    const int fpc = quad ^ (l15 & 3);   // fragment physical chunk
    for (int kt = 0; kt < KK / 32; ++kt) {
        const int cur = kt & 1;
        if (kt + 1 < KK / 32) {
            const int nbA = (1 - cur) * 4096;    // elems (128*32)
            const int nbB = (1 - cur) * 2048;    // elems (64*32)
            ASYNC16(gA + (kt + 1) * 32,           lA + nbA);
            ASYNC16(gA + (kt + 1) * 32 + 16 * KK, lA + nbA + 16 * 32);
            ASYNC16(gB + (kt + 1) * 32,           lB + nbB);
        }
        const bf16* cA = As + cur * 4096;
        const bf16* cB = Bs + cur * 2048;
        bf16x8 af[2], bfr[4];
        #pragma unroll
        for (int i = 0; i < 2; ++i)
            af[i] = *(const bf16x8*)(cA + (wave * 32 + i * 16 + l15) * 32 + fpc * 8);
        #pragma unroll
        for (int j = 0; j < 4; ++j)
            bfr[j] = *(const bf16x8*)(cB + (j * 16 + l15) * 32 + fpc * 8);
        #pragma unroll
        for (int i = 0; i < 2; ++i)
            #pragma unroll
            for (int j = 0; j < 4; ++j)
                acc[i][j] = (ORD == 0)
                    ? __builtin_amdgcn_mfma_f32_16x16x32_bf16(af[i], bfr[j], acc[i][j], 0, 0, 0)
                    : __builtin_amdgcn_mfma_f32_16x16x32_bf16(bfr[j], af[i], acc[i][j], 0, 0, 0);
        __syncthreads();
    }
}

// ---------------------------------------------------------------------------
// Kernel 1: QKV projection.  1-D grid of 2304 (64 tileM x 12 tileN x 3 z),
// XCD swizzle: tileM = u % 64 (36 sharers of an x-tile are 64-strided).
// z=0/1 use ORD=1 (pack 4 consecutive d per lane); z=2 ORD=0 (V^T store).
// ---------------------------------------------------------------------------
__global__ __launch_bounds__(256) void qkv_kernel(
    const bf16* __restrict__ xb,
    const bf16* __restrict__ Wqb, const float* __restrict__ bq,
    const bf16* __restrict__ Wkb, const float* __restrict__ bk,
    const bf16* __restrict__ Wvb, const float* __restrict__ bv,
    const float* __restrict__ addi_key, const float* __restrict__ addi_value,
    bf16* __restrict__ qbuf, bf16* __restrict__ kbuf, bf16* __restrict__ vtbuf)
{
    __shared__ __align__(16) bf16 As[2 * 128 * 32];
    __shared__ __align__(16) bf16 Bs[2 * 64 * 32];
    const int u = blockIdx.x;
    const int tileM = u & 63;
    const int r     = u >> 6;            // 0..35
    const int tileN = r % 12;
    const int z     = r / 12;            // 0..2
    const bf16* W     = (z == 0) ? Wqb : (z == 1) ? Wkb : Wvb;
    const float* bias = (z == 0) ? bq  : (z == 1) ? bk  : bv;

    floatx4 acc[2][4];
    #pragma unroll
    for (int i = 0; i < 2; ++i)
        #pragma unroll
        for (int j = 0; j < 4; ++j) { floatx4 zv = {0.f, 0.f, 0.f, 0.f}; acc[i][j] = zv; }

    const int lane = threadIdx.x & 63, wave = threadIdx.x >> 6;
    const int l15 = lane & 15, quad = lane >> 4;

    if (z == 2) {
        gemm_mainloop64<0>(xb, W, tileM, tileN, As, Bs, acc);
        // D: m = x-row sg (chunks quad*4+r), n = W-row o (l15)
        #pragma unroll
        for (int i = 0; i < 2; ++i) {
            const int sg0 = tileM * 128 + wave * 32 + i * 16 + quad * 4;
            const int b = sg0 >> 11, s0 = sg0 & 2047;
            #pragma unroll
            for (int j = 0; j < 4; ++j) {
                const int o = tileN * 64 + j * 16 + l15;
                const float bv_ = bias[o];
                const int h = o >> 6, d = o & 63;
                float vv[4];
                #pragma unroll
                for (int rr = 0; rr < 4; ++rr) {
                    vv[rr] = acc[i][j][rr] + bv_;
                    if (h < NSYN)
                        vv[rr] += addi_value[(((size_t)b * NSYN + h) * SS + s0 + rr) * HD + d];
                }
                bf16x4 pk = { (bf16)vv[0], (bf16)vv[1], (bf16)vv[2], (bf16)vv[3] };
                *(bf16x4*)(vtbuf + (((size_t)b * HH + h) * HD + d) * SS + s0) = pk;
            }
        }
    } else {
        gemm_mainloop64<1>(xb, W, tileM, tileN, As, Bs, acc);
        // D: m = W-row o (chunks quad*4+r), n = x-row sg (l15)
        #pragma unroll
        for (int i = 0; i < 2; ++i) {
            const int sg = tileM * 128 + wave * 32 + i * 16 + l15;
            const int b = sg >> 11, s = sg & 2047;
            #pragma unroll
            for (int j = 0; j < 4; ++j) {
                const int o0 = tileN * 64 + j * 16 + quad * 4;
                const int h = o0 >> 6, d0 = o0 & 63;
                float4 b4 = *(const float4*)(bias + o0);
                float vv[4] = { acc[i][j][0] + b4.x, acc[i][j][1] + b4.y,
                                acc[i][j][2] + b4.z, acc[i][j][3] + b4.w };
                if (z == 1 && h < NSYN) {
                    float4 a4 = *(const float4*)(addi_key +
                        (((size_t)b * NSYN + h) * SS + s) * HD + d0);
                    vv[0] += a4.x; vv[1] += a4.y; vv[2] += a4.z; vv[3] += a4.w;
                }
                if (z == 0) {
                    bf16x4 pk = { (bf16)(vv[0] * SCALE), (bf16)(vv[1] * SCALE),
                                  (bf16)(vv[2] * SCALE), (bf16)(vv[3] * SCALE) };
                    *(bf16x4*)(qbuf + (((size_t)b * HH + h) * SS + s) * HD + d0) = pk;
                } else {
                    bf16x4 pk = { (bf16)vv[0], (bf16)vv[1], (bf16)vv[2], (bf16)vv[3] };
                    *(bf16x4*)(kbuf + (((size_t)b * HH + h) * SS + s) * HD + d0) = pk;
                }
            }
        }
    }
}

// ---------------------------------------------------------------------------
// Kernel 2: flash attention, S^T/O^T, 4-wave blocks (256 thr), 32 q/wave,
// DOUBLE-BUFFERED K/V tiles, register-resident P (no Ps LDS): the S^T
// fragment (lane holds S[q=l15][key=j*16+quad*4+r]) is redistributed to the
// PV B-operand layout (P[q=l15][key=c*32+quad*8+e]) with permlane32_swap
// (route on key-bit b2 across lane^32) + permlane16_swap (route on key-bit
// b1 across lane^16), independently per q-subtile n.  LDS = 32KB; grid
// 768 = 48 bh x 16 qt (3 blocks/CU), XCD swizzle bh = u % 48.  s_setprio(1)
// around MFMA clusters (3 independent blocks/CU at different kt phases).
// No-max bounded softmax, deferred l-reduction.
// ---------------------------------------------------------------------------
__global__ __launch_bounds__(256, 3) void attn_kernel(
    const bf16* __restrict__ qbuf, const bf16* __restrict__ kbuf,
    const bf16* __restrict__ vtbuf, const float* __restrict__ ml2e,
    bf16* __restrict__ ctx)
{
    __shared__ __align__(16) bf16 Ks[2 * 64 * 64];
    __shared__ __align__(16) bf16 Vt[2 * 64 * 64];

    const int u  = blockIdx.x;
    const int bh = u % 48;              // b*12 + h
    const int qt = u / 48;              // 0..15
    const int b  = bh / 12;
    const int h  = bh % 12;
    const size_t bhs = ((size_t)b * HH + h) * SS * HD;  // same for vtbuf (HD*SS)
    const int tid = threadIdx.x, lane = tid & 63, wave = tid >> 6;  // 0..3
    const int l15 = lane & 15, quad = lane >> 4;
    const int q0 = qt * 128 + wave * 32;

    // staging: wave w stages K rows [w*16,w*16+16) and V^T rows likewise,
    // 2 insts each of 8 rows; phys chunk lane&7, swizzle ^ (row&7).
    const int sr  = wave * 16 + (lane >> 3);
    const int scl = (lane & 7) ^ ((lane >> 3) & 7);
    const bf16* gK = kbuf  + bhs + (size_t)sr * HD + scl * 8;
    const bf16* gV = vtbuf + bhs + (size_t)sr * SS + scl * 8;
    bf16* lK = Ks + (wave * 16) * 64;   // + lane*16B implicit
    bf16* lV = Vt + (wave * 16) * 64;

    // Q fragments (B operand: n = q = l15): 2 q-subtiles x 2 k-chunks
    bf16x8 qf[2][2];
    #pragma unroll
    for (int n = 0; n < 2; ++n)
        #pragma unroll
        for (int c = 0; c < 2; ++c)
            qf[n][c] = *(const bf16x8*)(qbuf + bhs +
                (size_t)(q0 + n * 16 + l15) * HD + c * 32 + quad * 8);

    floatx4 acco[2][4];   // O^T: acco[n][t][r] = O[q=n*16+l15][d=t*16+quad*4+r]
    #pragma unroll
    for (int n = 0; n < 2; ++n)
        #pragma unroll
        for (int t = 0; t < 4; ++t) { floatx4 zv = {0.f, 0.f, 0.f, 0.f}; acco[n][t] = zv; }
    float lrun[2] = { 0.f, 0.f };       // per-lane partial; reduced after loop

    const float* mb = ml2e + (size_t)b * SS;

    // prefetch kt=0 into buffer 0
    #pragma unroll
    for (int p = 0; p < 2; ++p) {
        ASYNC16(gK + (size_t)p * 8 * HD,  lK + p * 512);
        ASYNC16(gV + (size_t)p * 8 * SS,  lV + p * 512);
    }
    __syncthreads();

    for (int kt = 0; kt < SS / 64; ++kt) {
        const int cur = kt & 1;
        if (kt + 1 < SS / 64) {
            const int nb = (1 - cur) * 4096;    // elems (64*64)
            #pragma unroll
            for (int p = 0; p < 2; ++p) {
                ASYNC16(gK + ((size_t)(kt + 1) * 64 + p * 8) * HD, lK + nb + p * 512);
                ASYNC16(gV + (size_t)p * 8 * SS + (kt + 1) * 64,   lV + nb + p * 512);
            }
        }
        const bf16* cK = Ks + cur * 4096;
        const bf16* cV = Vt + cur * 4096;

        // S^T = K·Q^T : sacc[n][j][r] = S[q=n*16+l15][key=j*16+quad*4+r]
        floatx4 sacc[2][4];
        #pragma unroll
        for (int n = 0; n < 2; ++n)
            #pragma unroll
            for (int j = 0; j < 4; ++j) { floatx4 zv = {0.f, 0.f, 0.f, 0.f}; sacc[n][j] = zv; }
        __builtin_amdgcn_s_setprio(1);
        #pragma unroll
        for (int c = 0; c < 2; ++c) {
            const int pc = (4 * c + quad) ^ (l15 & 7);
            #pragma unroll
            for (int j = 0; j < 4; ++j) {
                bf16x8 af = *(const bf16x8*)(cK + (j * 16 + l15) * 64 + pc * 8);
                #pragma unroll
                for (int n = 0; n < 2; ++n)
                    sacc[n][j] = __builtin_amdgcn_mfma_f32_16x16x32_bf16(af, qf[n][c], sacc[n][j], 0, 0, 0);
            }
        }
        __builtin_amdgcn_s_setprio(0);

        // p = exp2(s*log2e + mask*log2e); accumulate per-lane l; pack to u32.
        // Word (key-block B=key/4 bits b3b2b1b0, half hf): src register
        // w[n][j=2*b3+b2][hf] at lane quad=(b1,b0).
        unsigned int w[2][4][2];
        #pragma unroll
        for (int j = 0; j < 4; ++j) {
            float4 mk = *(const float4*)(mb + kt * 64 + j * 16 + quad * 4);
            #pragma unroll
            for (int n = 0; n < 2; ++n) {
                float p0 = EXP2(__builtin_fmaf(sacc[n][j][0], LOG2E, mk.x));
                float p1 = EXP2(__builtin_fmaf(sacc[n][j][1], LOG2E, mk.y));
                float p2 = EXP2(__builtin_fmaf(sacc[n][j][2], LOG2E, mk.z));
                float p3 = EXP2(__builtin_fmaf(sacc[n][j][3], LOG2E, mk.w));
                lrun[n] += (p0 + p1) + (p2 + p3);
                union { bf16x4 v; unsigned int u2[2]; } pk;
                pk.v = (bf16x4){ (bf16)p0, (bf16)p1, (bf16)p2, (bf16)p3 };
                w[n][j][0] = pk.u2[0];
                w[n][j][1] = pk.u2[1];
            }
        }
        // round 1: route on key-bit b2 across lane^32
        #pragma unroll
        for (int n = 0; n < 2; ++n) {
            pl32_swap(w[n][0][0], w[n][1][0]);  pl32_swap(w[n][0][1], w[n][1][1]);
            pl32_swap(w[n][2][0], w[n][3][0]);  pl32_swap(w[n][2][1], w[n][3][1]);
        }
        // round 2: route on key-bit b1 across lane^16
        #pragma unroll
        for (int n = 0; n < 2; ++n) {
            pl16_swap(w[n][0][0], w[n][1][0]);  pl16_swap(w[n][0][1], w[n][1][1]);
            pl16_swap(w[n][2][0], w[n][3][0]);  pl16_swap(w[n][2][1], w[n][3][1]);
        }
        // now w[n][2*c + b0][hf] = P[q=n*16+l15][key = c*32 + quad*8 + 4*b0 + 2*hf +{0,1}]
        union { unsigned int u2[4]; bf16x8 v; } pb[2][2];
        #pragma unroll
        for (int n = 0; n < 2; ++n) {
            pb[n][0].u2[0] = w[n][0][0]; pb[n][0].u2[1] = w[n][0][1];
            pb[n][0].u2[2] = w[n][1][0]; pb[n][0].u2[3] = w[n][1][1];
            pb[n][1].u2[0] = w[n][2][0]; pb[n][1].u2[1] = w[n][2][1];
            pb[n][1].u2[2] = w[n][3][0]; pb[n][1].u2[3] = w[n][3][1];
        }

        // O^T += V^T·P^T  (P fragment straight from registers)
        __builtin_amdgcn_s_setprio(1);
        #pragma unroll
        for (int c = 0; c < 2; ++c) {
            const int pc = (4 * c + quad) ^ (l15 & 7);
            #pragma unroll
            for (int t = 0; t < 4; ++t) {
                bf16x8 af = *(const bf16x8*)(cV + (t * 16 + l15) * 64 + pc * 8);
                #pragma unroll
                for (int n = 0; n < 2; ++n)
                    acco[n][t] = __builtin_amdgcn_mfma_f32_16x16x32_bf16(af, pb[n][c].v, acco[n][t], 0, 0, 0);
            }
        }
        __builtin_amdgcn_s_setprio(0);
        __syncthreads();   // drain prefetch (after compute) + free cur buffer
    }

    // deferred cross-quad l reduction (sum over keys commutes)
    #pragma unroll
    for (int n = 0; n < 2; ++n) {
        lrun[n] += __shfl_xor(lrun[n], 16);
        lrun[n] += __shfl_xor(lrun[n], 32);
    }

    // ctx[B,S,DM]: row q = q0 + n*16 + l15, col = h*64 + t*16 + quad*4 (x4)
    #pragma unroll
    for (int n = 0; n < 2; ++n) {
        const float inv = 1.0f / lrun[n];
        bf16* crow = ctx + ((size_t)(b * SS + q0 + n * 16 + l15)) * DM + h * HD;
        #pragma unroll
        for (int t = 0; t < 4; ++t) {
            bf16x4 ov = { (bf16)(acco[n][t][0] * inv), (bf16)(acco[n][t][1] * inv),
                          (bf16)(acco[n][t][2] * inv), (bf16)(acco[n][t][3] * inv) };
            *(bf16x4*)(crow + t * 16 + quad * 4) = ov;
        }
    }
}

// ---------------------------------------------------------------------------
// Kernel 3: output projection + bias + residual x(fp32) -> h (bf16).
// 1-D grid of 768 (64 tileM x 12 tileN), XCD swizzle tileM = u % 64.
// ---------------------------------------------------------------------------
__global__ __launch_bounds__(256) void oproj_kernel(
    const bf16* __restrict__ ctx, const bf16* __restrict__ Wob,
    const float* __restrict__ bo, const float* __restrict__ x,
    bf16* __restrict__ hbuf)
{
    __shared__ __align__(16) bf16 As[2 * 128 * 32];
    __shared__ __align__(16) bf16 Bs[2 * 64 * 32];
    const int u = blockIdx.x;
    const int tileM = u & 63;
    const int tileN = u >> 6;           // 0..11

    floatx4 acc[2][4];
    #pragma unroll
    for (int i = 0; i < 2; ++i)
        #pragma unroll
        for (int j = 0; j < 4; ++j) { floatx4 zv = {0.f, 0.f, 0.f, 0.f}; acc[i][j] = zv; }

    gemm_mainloop64<1>(ctx, Wob, tileM, tileN, As, Bs, acc);

    const int lane = threadIdx.x & 63, wave = threadIdx.x >> 6;
    const int l15 = lane & 15, quad = lane >> 4;
    #pragma unroll
    for (int i = 0; i < 2; ++i) {
        const int sg = tileM * 128 + wave * 32 + i * 16 + l15;
        #pragma unroll
        for (int j = 0; j < 4; ++j) {
            const int o0 = tileN * 64 + j * 16 + quad * 4;
            float4 b4 = *(const float4*)(bo + o0);
            float4 r4 = *(const float4*)(x + (size_t)sg * DM + o0);
            bf16x4 pk = { (bf16)(acc[i][j][0] + b4.x + r4.x),
                          (bf16)(acc[i][j][1] + b4.y + r4.y),
                          (bf16)(acc[i][j][2] + b4.z + r4.z),
                          (bf16)(acc[i][j][3] + b4.w + r4.w) };
            *(bf16x4*)(hbuf + (size_t)sg * DM + o0) = pk;
        }
    }
}

// ---------------------------------------------------------------------------
// Kernel 4: LayerNorm, one wave per row (768 elems = 12/lane), eps=1e-12.
// ---------------------------------------------------------------------------
__global__ __launch_bounds__(256) void ln_kernel(
    const bf16* __restrict__ hbuf, const float* __restrict__ g,
    const float* __restrict__ be, float* __restrict__ out)
{
    const int row  = blockIdx.x * 4 + (threadIdx.x >> 6);
    const int lane = threadIdx.x & 63;
    const bf16* hr = hbuf + (size_t)row * DM;

    bf16x8 va = *(const bf16x8*)(hr + lane * 8);          // elems [0,512)
    bf16x4 vb = *(const bf16x4*)(hr + 512 + lane * 4);    // elems [512,768)
    float v[12];
    #pragma unroll
    for (int i = 0; i < 8; ++i) v[i] = (float)va[i];
    #pragma unroll
    for (int i = 0; i < 4; ++i) v[8 + i] = (float)vb[i];

    float s = 0.f;
    #pragma unroll
    for (int i = 0; i < 12; ++i) s += v[i];
    #pragma unroll
    for (int m = 1; m < 64; m <<= 1) s += __shfl_xor(s, m);
    const float mu = s * (1.0f / DM);

    float s2 = 0.f;
    #pragma unroll
    for (int i = 0; i < 12; ++i) { v[i] -= mu; s2 += v[i] * v[i]; }
    #pragma unroll
    for (int m = 1; m < 64; m <<= 1) s2 += __shfl_xor(s2, m);
    const float rsv = rsqrtf(s2 * (1.0f / DM) + 1e-12f);

    float* orow = out + (size_t)row * DM;
    const int c0 = lane * 8, c1 = 512 + lane * 4;
    float4 g0 = *(const float4*)(g + c0),     g1 = *(const float4*)(g + c0 + 4);
    float4 g2 = *(const float4*)(g + c1);
    float4 b0 = *(const float4*)(be + c0),    b1 = *(const float4*)(be + c0 + 4);
    float4 b2 = *(const float4*)(be + c1);
    float4 o0 = { v[0]*rsv*g0.x + b0.x, v[1]*rsv*g0.y + b0.y,
                  v[2]*rsv*g0.z + b0.z, v[3]*rsv*g0.w + b0.w };
    float4 o1 = { v[4]*rsv*g1.x + b1.x, v[5]*rsv*g1.y + b1.y,
                  v[6]*rsv*g1.z + b1.z, v[7]*rsv*g1.w + b1.w };
    float4 o2 = { v[8]*rsv*g2.x + b2.x, v[9]*rsv*g2.y + b2.y,
                  v[10]*rsv*g2.z + b2.z, v[11]*rsv*g2.w + b2.w };
    *(float4*)(orow + c0)     = o0;
    *(float4*)(orow + c0 + 4) = o1;
    *(float4*)(orow + c1)     = o2;
}

// ---------------------------------------------------------------------------
extern "C" void kernel_launch(void* const* d_in, const int* in_sizes, int n_in,
                              void* d_out, int out_size, void* d_ws, size_t ws_size,
                              hipStream_t stream)
{
    const float* x    = (const float*)d_in[0];
    const float* mask = (const float*)d_in[1];
    const float* akey = (const float*)d_in[2];
    const float* aval = (const float*)d_in[3];
    const float* Wq = (const float*)d_in[4];  const float* bq = (const float*)d_in[5];
    const float* Wk = (const float*)d_in[6];  const float* bk = (const float*)d_in[7];
    const float* Wv = (const float*)d_in[8];  const float* bv = (const float*)d_in[9];
    const float* Wo = (const float*)d_in[10]; const float* bo = (const float*)d_in[11];
    const float* lng = (const float*)d_in[12]; const float* lnb = (const float*)d_in[13];
    float* outp = (float*)d_out;

    const size_t nqkv = (size_t)BB * HH * SS * HD;   // 6,291,456 elems
    char* ws = (char*)d_ws;
    bf16*  xb   = (bf16*)ws;   ws += N_X  * sizeof(bf16);
    bf16*  Wqb  = (bf16*)ws;   ws += N_W  * sizeof(bf16);
    bf16*  Wkb  = (bf16*)ws;   ws += N_W  * sizeof(bf16);
    bf16*  Wvb  = (bf16*)ws;   ws += N_W  * sizeof(bf16);
    bf16*  Wob  = (bf16*)ws;   ws += N_W  * sizeof(bf16);
    float* ml2e = (float*)ws;  ws += N_M  * sizeof(float);
    bf16*  qbuf = (bf16*)ws;   ws += nqkv * sizeof(bf16);
    bf16*  kbuf = (bf16*)ws;   ws += nqkv * sizeof(bf16);
    bf16*  vtbuf= (bf16*)ws;   ws += nqkv * sizeof(bf16);
    bf16*  ctxb = (bf16*)ws;   ws += nqkv * sizeof(bf16);
    bf16*  hbuf = (bf16*)ws;   ws += nqkv * sizeof(bf16);
    // total ~80 MB of d_ws

    const size_t ncvt = (N_X + 4 * N_W + N_M) / 4;       // threads, 4 elems each
    const int cvt_blocks = (int)((ncvt + 255) / 256);
    cvt_kernel<<<cvt_blocks, 256, 0, stream>>>(x, Wq, Wk, Wv, Wo, mask,
                                               xb, Wqb, Wkb, Wvb, Wob, ml2e);

    qkv_kernel<<<2304, 256, 0, stream>>>(xb, Wqb, bq, Wkb, bk, Wvb, bv, akey, aval,
                                         qbuf, kbuf, vtbuf);
    attn_kernel<<<768, 256, 0, stream>>>(qbuf, kbuf, vtbuf, ml2e, ctxb);
    oproj_kernel<<<768, 256, 0, stream>>>(ctxb, Wob, bo, x, hbuf);
    ln_kernel<<<MM / 4, 256, 0, stream>>>(hbuf, lng, lnb, outp);
}

// Round 3
// 266.215 us; speedup vs baseline: 1.0879x; 1.0282x over previous
//
#include <hip/hip_runtime.h>

// BertAttention fused: fp32 in/out, bf16 MFMA compute internally.
// cvt(fp32->bf16, + mask*log2e) -> QKV proj (async dbuf GEMM 128x64 tiles,
// XCD swizzle, Q pre-scaled by 1/8*log2e) -> flash attention (S^T/O^T, 4-wave
// blocks, 32q/wave, dbuf K/V, mask-initialized QK^T accumulator (no fma, no
// zero-init), register-resident P via permlane16/32_swap, l-denominator via
// ones-MFMA (no VALU adds, no final shuffle), s_setprio around MFMA clusters)
// -> out proj + residual -> LN.
// B=4 S=2048 DM=768 H=12 HD=64 NSYN=4, scale=1/8, eps=1e-12.

typedef __bf16 bf16;
typedef __bf16 bf16x8 __attribute__((ext_vector_type(8)));
typedef __bf16 bf16x4 __attribute__((ext_vector_type(4)));
typedef float floatx4 __attribute__((ext_vector_type(4)));
typedef unsigned int uint2v __attribute__((ext_vector_type(2)));

#define BB 4
#define SS 2048
#define DM 768
#define HH 12
#define HD 64
#define NSYN 4
#define MM (BB*SS)          // 8192 rows
#define KK DM               // 768
#define SCALE 0.125f
#define LOG2E 1.4426950408889634f
#define QSCALE (SCALE * LOG2E)      // folded into Q at projection time

#define N_X   ((size_t)MM * DM)      // 6,291,456
#define N_W   ((size_t)DM * DM)      // 589,824
#define N_M   ((size_t)BB * SS)      // 8,192 (mask)

#if __has_builtin(__builtin_amdgcn_exp2f)
#define EXP2(x) __builtin_amdgcn_exp2f(x)
#else
#define EXP2(x) exp2f(x)
#endif

// async 16B/lane global->LDS copy; lane i of the wave lands at ldsbase + i*16
#define ASYNC16(gp, lp)                                                        \
    __builtin_amdgcn_global_load_lds(                                          \
        (const __attribute__((address_space(1))) unsigned int*)(gp),           \
        (__attribute__((address_space(3))) unsigned int*)(lp), 16, 0, 0)

// gfx950 dual-register half-swaps (VALU, full-rate).
static __device__ __forceinline__ void pl32_swap(unsigned int& a, unsigned int& b) {
#if __has_builtin(__builtin_amdgcn_permlane32_swap)
    uint2v r = __builtin_amdgcn_permlane32_swap(a, b, false, false);
    a = r[0]; b = r[1];
#else
    asm volatile("v_permlane32_swap_b32 %0, %1" : "+v"(a), "+v"(b));
#endif
}
static __device__ __forceinline__ void pl16_swap(unsigned int& a, unsigned int& b) {
#if __has_builtin(__builtin_amdgcn_permlane16_swap)
    uint2v r = __builtin_amdgcn_permlane16_swap(a, b, false, false);
    a = r[0]; b = r[1];
#else
    asm volatile("v_permlane16_swap_b32 %0, %1" : "+v"(a), "+v"(b));
#endif
}

// ---------------------------------------------------------------------------
// Kernel 0: fp32 -> bf16 for x and 4 weights; mask -> mask*LOG2E (fp32).
// ---------------------------------------------------------------------------
__global__ __launch_bounds__(256) void cvt_kernel(
    const float* __restrict__ x,
    const float* __restrict__ Wq, const float* __restrict__ Wk,
    const float* __restrict__ Wv, const float* __restrict__ Wo,
    const float* __restrict__ mask,
    bf16* __restrict__ xb,
    bf16* __restrict__ Wqb, bf16* __restrict__ Wkb,
    bf16* __restrict__ Wvb, bf16* __restrict__ Wob,
    float* __restrict__ ml2e)
{
    const size_t nx4 = N_X / 4, nw4 = N_W / 4, nm4 = N_M / 4;
    size_t i = (size_t)blockIdx.x * blockDim.x + threadIdx.x;
    if (i >= nx4 + 4 * nw4) {
        size_t off = i - nx4 - 4 * nw4;
        if (off < nm4) {
            float4 m = *(const float4*)(mask + off * 4);
            float4 o = { m.x * LOG2E, m.y * LOG2E, m.z * LOG2E, m.w * LOG2E };
            *(float4*)(ml2e + off * 4) = o;
        }
        return;
    }
    const float* src; bf16* dst; size_t off;
    if (i < nx4)                { src = x;  dst = xb;  off = i; }
    else if (i < nx4 + nw4)     { src = Wq; dst = Wqb; off = i - nx4; }
    else if (i < nx4 + 2*nw4)   { src = Wk; dst = Wkb; off = i - nx4 - nw4; }
    else if (i < nx4 + 3*nw4)   { src = Wv; dst = Wvb; off = i - nx4 - 2*nw4; }
    else                        { src = Wo; dst = Wob; off = i - nx4 - 3*nw4; }
    float4 v = *(const float4*)(src + off * 4);
    bf16x4 o = { (bf16)v.x, (bf16)v.y, (bf16)v.z, (bf16)v.w };
    *(bf16x4*)(dst + off * 4) = o;
}

// ---------------------------------------------------------------------------
// GEMM mainloop, 128(M) x 64(N) tile = A[M,K] · Bw[N,K]^T, double-buffered
// async staging, XOR chunk swizzle.  4 waves; wave w owns M rows
// [w*32, w*32+32) x all 64 N.  acc[2][4].
// ORD=0: D[m=A-row(quad*4+r)][n=B-row(l15)];
// ORD=1: swapped -> D[m=B-row(quad*4+r)][n=A-row(l15)].
// ---------------------------------------------------------------------------
template<int ORD>
__device__ __forceinline__ void gemm_mainloop64(
    const bf16* __restrict__ A, const bf16* __restrict__ Bw,
    int tileM, int tileN, bf16* As, bf16* Bs, floatx4 acc[2][4])
{
    const int tid  = threadIdx.x;
    const int lane = tid & 63;
    const int wave = tid >> 6;
    const int l15 = lane & 15, quad = lane >> 4;

    const int r0a = wave * 32 + (lane >> 2);
    const int r0b = wave * 16 + (lane >> 2);
    const int cl  = (lane & 3) ^ ((lane >> 2) & 3);   // swizzled chunk (r0&3)
    const bf16* gA = A  + (size_t)(tileM * 128 + r0a) * KK + cl * 8;
    const bf16* gB = Bw + (size_t)(tileN *  64 + r0b) * KK + cl * 8;
    bf16* lA = As + (wave * 32) * 32;   // + lane*16B implicit (HW)
    bf16* lB = Bs + (wave * 16) * 32;

    ASYNC16(gA,           lA);
    ASYNC16(gA + 16 * KK, lA + 16 * 32);
    ASYNC16(gB,           lB);
    __syncthreads();

    const int fpc = quad ^ (l15 & 3);   // fragment physical chunk
    for (int kt = 0; kt < KK / 32; ++kt) {
        const int cur = kt & 1;
        if (kt + 1 < KK / 32) {
            const int nbA = (1 - cur) * 4096;    // elems (128*32)
            const int nbB = (1 - cur) * 2048;    // elems (64*32)
            ASYNC16(gA + (kt + 1) * 32,           lA + nbA);
            ASYNC16(gA + (kt + 1) * 32 + 16 * KK, lA + nbA + 16 * 32);
            ASYNC16(gB + (kt + 1) * 32,           lB + nbB);
        }
        const bf16* cA = As + cur * 4096;
        const bf16* cB = Bs + cur * 2048;
        bf16x8 af[2], bfr[4];
        #pragma unroll
        for (int i = 0; i < 2; ++i)
            af[i] = *(const bf16x8*)(cA + (wave * 32 + i * 16 + l15) * 32 + fpc * 8);
        #pragma unroll
        for (int j = 0; j < 4; ++j)
            bfr[j] = *(const bf16x8*)(cB + (j * 16 + l15) * 32 + fpc * 8);
        #pragma unroll
        for (int i = 0; i < 2; ++i)
            #pragma unroll
            for (int j = 0; j < 4; ++j)
                acc[i][j] = (ORD == 0)
                    ? __builtin_amdgcn_mfma_f32_16x16x32_bf16(af[i], bfr[j], acc[i][j], 0, 0, 0)
                    : __builtin_amdgcn_mfma_f32_16x16x32_bf16(bfr[j], af[i], acc[i][j], 0, 0, 0);
        __syncthreads();
    }
}

// ---------------------------------------------------------------------------
// Kernel 1: QKV projection.  1-D grid of 2304 (64 tileM x 12 tileN x 3 z),
// XCD swizzle: tileM = u % 64 (36 sharers of an x-tile are 64-strided).
// z=0/1 use ORD=1 (pack 4 consecutive d per lane); z=2 ORD=0 (V^T store).
// Q is scaled by SCALE*LOG2E so attention scores come out in log2 domain.
// ---------------------------------------------------------------------------
__global__ __launch_bounds__(256) void qkv_kernel(
    const bf16* __restrict__ xb,
    const bf16* __restrict__ Wqb, const float* __restrict__ bq,
    const bf16* __restrict__ Wkb, const float* __restrict__ bk,
    const bf16* __restrict__ Wvb, const float* __restrict__ bv,
    const float* __restrict__ addi_key, const float* __restrict__ addi_value,
    bf16* __restrict__ qbuf, bf16* __restrict__ kbuf, bf16* __restrict__ vtbuf)
{
    __shared__ __align__(16) bf16 As[2 * 128 * 32];
    __shared__ __align__(16) bf16 Bs[2 * 64 * 32];
    const int u = blockIdx.x;
    const int tileM = u & 63;
    const int r     = u >> 6;            // 0..35
    const int tileN = r % 12;
    const int z     = r / 12;            // 0..2
    const bf16* W     = (z == 0) ? Wqb : (z == 1) ? Wkb : Wvb;
    const float* bias = (z == 0) ? bq  : (z == 1) ? bk  : bv;

    floatx4 acc[2][4];
    #pragma unroll
    for (int i = 0; i < 2; ++i)
        #pragma unroll
        for (int j = 0; j < 4; ++j) { floatx4 zv = {0.f, 0.f, 0.f, 0.f}; acc[i][j] = zv; }

    const int lane = threadIdx.x & 63, wave = threadIdx.x >> 6;
    const int l15 = lane & 15, quad = lane >> 4;

    if (z == 2) {
        gemm_mainloop64<0>(xb, W, tileM, tileN, As, Bs, acc);
        // D: m = x-row sg (chunks quad*4+r), n = W-row o (l15)
        #pragma unroll
        for (int i = 0; i < 2; ++i) {
            const int sg0 = tileM * 128 + wave * 32 + i * 16 + quad * 4;
            const int b = sg0 >> 11, s0 = sg0 & 2047;
            #pragma unroll
            for (int j = 0; j < 4; ++j) {
                const int o = tileN * 64 + j * 16 + l15;
                const float bv_ = bias[o];
                const int h = o >> 6, d = o & 63;
                float vv[4];
                #pragma unroll
                for (int rr = 0; rr < 4; ++rr) {
                    vv[rr] = acc[i][j][rr] + bv_;
                    if (h < NSYN)
                        vv[rr] += addi_value[(((size_t)b * NSYN + h) * SS + s0 + rr) * HD + d];
                }
                bf16x4 pk = { (bf16)vv[0], (bf16)vv[1], (bf16)vv[2], (bf16)vv[3] };
                *(bf16x4*)(vtbuf + (((size_t)b * HH + h) * HD + d) * SS + s0) = pk;
            }
        }
    } else {
        gemm_mainloop64<1>(xb, W, tileM, tileN, As, Bs, acc);
        // D: m = W-row o (chunks quad*4+r), n = x-row sg (l15)
        #pragma unroll
        for (int i = 0; i < 2; ++i) {
            const int sg = tileM * 128 + wave * 32 + i * 16 + l15;
            const int b = sg >> 11, s = sg & 2047;
            #pragma unroll
            for (int j = 0; j < 4; ++j) {
                const int o0 = tileN * 64 + j * 16 + quad * 4;
                const int h = o0 >> 6, d0 = o0 & 63;
                float4 b4 = *(const float4*)(bias + o0);
                float vv[4] = { acc[i][j][0] + b4.x, acc[i][j][1] + b4.y,
                                acc[i][j][2] + b4.z, acc[i][j][3] + b4.w };
                if (z == 1 && h < NSYN) {
                    float4 a4 = *(const float4*)(addi_key +
                        (((size_t)b * NSYN + h) * SS + s) * HD + d0);
                    vv[0] += a4.x; vv[1] += a4.y; vv[2] += a4.z; vv[3] += a4.w;
                }
                if (z == 0) {
                    bf16x4 pk = { (bf16)(vv[0] * QSCALE), (bf16)(vv[1] * QSCALE),
                                  (bf16)(vv[2] * QSCALE), (bf16)(vv[3] * QSCALE) };
                    *(bf16x4*)(qbuf + (((size_t)b * HH + h) * SS + s) * HD + d0) = pk;
                } else {
                    bf16x4 pk = { (bf16)vv[0], (bf16)vv[1], (bf16)vv[2], (bf16)vv[3] };
                    *(bf16x4*)(kbuf + (((size_t)b * HH + h) * SS + s) * HD + d0) = pk;
                }
            }
        }
    }
}

// ---------------------------------------------------------------------------
// Kernel 2: flash attention, S^T/O^T, 4-wave blocks (256 thr), 32 q/wave,
// DOUBLE-BUFFERED K/V tiles.  Q pre-scaled by 1/8*log2e, so S = log2-domain
// score; the QK^T accumulator is INITIALIZED with mask*log2e (C-operand of
// the first MFMA) -> p = exp2(sacc) directly: no zero-init, no fma.
// Register-resident P via permlane32/16_swap (route key-bits b2/b1 across
// lane^32/lane^16).  l-denominator via ones-MFMA: lacc[n] += ones16x32 ·
// P-chunk, giving the full 64-key sum per lane (no VALU adds, no final
// shuffle).  LDS = 32KB; grid 768 = 48 bh x 16 qt (3 blocks/CU), XCD swizzle
// bh = u % 48.  s_setprio(1) around MFMA clusters.
// ---------------------------------------------------------------------------
__global__ __launch_bounds__(256, 3) void attn_kernel(
    const bf16* __restrict__ qbuf, const bf16* __restrict__ kbuf,
    const bf16* __restrict__ vtbuf, const float* __restrict__ ml2e,
    bf16* __restrict__ ctx)
{
    __shared__ __align__(16) bf16 Ks[2 * 64 * 64];
    __shared__ __align__(16) bf16 Vt[2 * 64 * 64];

    const int u  = blockIdx.x;
    const int bh = u % 48;              // b*12 + h
    const int qt = u / 48;              // 0..15
    const int b  = bh / 12;
    const int h  = bh % 12;
    const size_t bhs = ((size_t)b * HH + h) * SS * HD;  // same for vtbuf (HD*SS)
    const int tid = threadIdx.x, lane = tid & 63, wave = tid >> 6;  // 0..3
    const int l15 = lane & 15, quad = lane >> 4;
    const int q0 = qt * 128 + wave * 32;

    // staging: wave w stages K rows [w*16,w*16+16) and V^T rows likewise,
    // 2 insts each of 8 rows; phys chunk lane&7, swizzle ^ (row&7).
    const int sr  = wave * 16 + (lane >> 3);
    const int scl = (lane & 7) ^ ((lane >> 3) & 7);
    const bf16* gK = kbuf  + bhs + (size_t)sr * HD + scl * 8;
    const bf16* gV = vtbuf + bhs + (size_t)sr * SS + scl * 8;
    bf16* lK = Ks + (wave * 16) * 64;   // + lane*16B implicit
    bf16* lV = Vt + (wave * 16) * 64;

    // Q fragments (B operand: n = q = l15): 2 q-subtiles x 2 k-chunks
    bf16x8 qf[2][2];
    #pragma unroll
    for (int n = 0; n < 2; ++n)
        #pragma unroll
        for (int c = 0; c < 2; ++c)
            qf[n][c] = *(const bf16x8*)(qbuf + bhs +
                (size_t)(q0 + n * 16 + l15) * HD + c * 32 + quad * 8);

    // all-ones A fragment for the l-denominator MFMA
    bf16x8 ones;
    #pragma unroll
    for (int e = 0; e < 8; ++e) ones[e] = (bf16)1.0f;

    floatx4 acco[2][4];   // O^T: acco[n][t][r] = O[q=n*16+l15][d=t*16+quad*4+r]
    #pragma unroll
    for (int n = 0; n < 2; ++n)
        #pragma unroll
        for (int t = 0; t < 4; ++t) { floatx4 zv = {0.f, 0.f, 0.f, 0.f}; acco[n][t] = zv; }
    floatx4 lacc[2];      // l: every component = full key-sum for q=n*16+l15
    { floatx4 zv = {0.f, 0.f, 0.f, 0.f}; lacc[0] = zv; lacc[1] = zv; }

    const float* mb = ml2e + (size_t)b * SS;

    // prefetch kt=0 into buffer 0
    #pragma unroll
    for (int p = 0; p < 2; ++p) {
        ASYNC16(gK + (size_t)p * 8 * HD,  lK + p * 512);
        ASYNC16(gV + (size_t)p * 8 * SS,  lV + p * 512);
    }
    __syncthreads();

    for (int kt = 0; kt < SS / 64; ++kt) {
        const int cur = kt & 1;
        if (kt + 1 < SS / 64) {
            const int nb = (1 - cur) * 4096;    // elems (64*64)
            #pragma unroll
            for (int p = 0; p < 2; ++p) {
                ASYNC16(gK + ((size_t)(kt + 1) * 64 + p * 8) * HD, lK + nb + p * 512);
                ASYNC16(gV + (size_t)p * 8 * SS + (kt + 1) * 64,   lV + nb + p * 512);
            }
        }
        const bf16* cK = Ks + cur * 4096;
        const bf16* cV = Vt + cur * 4096;

        // S^T = K·Q^T + mask-init : sacc[n][j][r] = log2-score + mask*log2e
        // for [q=n*16+l15][key=j*16+quad*4+r]  (mask is q-independent)
        floatx4 sacc[2][4];
        #pragma unroll
        for (int j = 0; j < 4; ++j) {
            float4 mk = *(const float4*)(mb + kt * 64 + j * 16 + quad * 4);
            floatx4 mv = { mk.x, mk.y, mk.z, mk.w };
            sacc[0][j] = mv;
            sacc[1][j] = mv;
        }
        __builtin_amdgcn_s_setprio(1);
        #pragma unroll
        for (int c = 0; c < 2; ++c) {
            const int pc = (4 * c + quad) ^ (l15 & 7);
            #pragma unroll
            for (int j = 0; j < 4; ++j) {
                bf16x8 af = *(const bf16x8*)(cK + (j * 16 + l15) * 64 + pc * 8);
                #pragma unroll
                for (int n = 0; n < 2; ++n)
                    sacc[n][j] = __builtin_amdgcn_mfma_f32_16x16x32_bf16(af, qf[n][c], sacc[n][j], 0, 0, 0);
            }
        }
        __builtin_amdgcn_s_setprio(0);

        // p = exp2(sacc); pack to u32.  Word (key-block bits b3b2b1b0, half
        // hf): src register w[n][j=2*b3+b2][hf] at lane quad=(b1,b0).
        unsigned int w[2][4][2];
        #pragma unroll
        for (int j = 0; j < 4; ++j) {
            #pragma unroll
            for (int n = 0; n < 2; ++n) {
                float p0 = EXP2(sacc[n][j][0]);
                float p1 = EXP2(sacc[n][j][1]);
                float p2 = EXP2(sacc[n][j][2]);
                float p3 = EXP2(sacc[n][j][3]);
                union { bf16x4 v; unsigned int u2[2]; } pk;
                pk.v = (bf16x4){ (bf16)p0, (bf16)p1, (bf16)p2, (bf16)p3 };
                w[n][j][0] = pk.u2[0];
                w[n][j][1] = pk.u2[1];
            }
        }
        // round 1: route on key-bit b2 across lane^32
        #pragma unroll
        for (int n = 0; n < 2; ++n) {
            pl32_swap(w[n][0][0], w[n][1][0]);  pl32_swap(w[n][0][1], w[n][1][1]);
            pl32_swap(w[n][2][0], w[n][3][0]);  pl32_swap(w[n][2][1], w[n][3][1]);
        }
        // round 2: route on key-bit b1 across lane^16
        #pragma unroll
        for (int n = 0; n < 2; ++n) {
            pl16_swap(w[n][0][0], w[n][1][0]);  pl16_swap(w[n][0][1], w[n][1][1]);
            pl16_swap(w[n][2][0], w[n][3][0]);  pl16_swap(w[n][2][1], w[n][3][1]);
        }
        // now w[n][2*c + b0][hf] = P[q=n*16+l15][key = c*32 + quad*8 + 4*b0 + 2*hf +{0,1}]
        union { unsigned int u2[4]; bf16x8 v; } pb[2][2];
        #pragma unroll
        for (int n = 0; n < 2; ++n) {
            pb[n][0].u2[0] = w[n][0][0]; pb[n][0].u2[1] = w[n][0][1];
            pb[n][0].u2[2] = w[n][1][0]; pb[n][0].u2[3] = w[n][1][1];
            pb[n][1].u2[0] = w[n][2][0]; pb[n][1].u2[1] = w[n][2][1];
            pb[n][1].u2[2] = w[n][3][0]; pb[n][1].u2[3] = w[n][3][1];
        }

        // O^T += V^T·P^T ; l += ones·P^T  (P fragments straight from registers)
        __builtin_amdgcn_s_setprio(1);
        #pragma unroll
        for (int c = 0; c < 2; ++c) {
            const int pc = (4 * c + quad) ^ (l15 & 7);
            #pragma unroll
            for (int n = 0; n < 2; ++n)
                lacc[n] = __builtin_amdgcn_mfma_f32_16x16x32_bf16(ones, pb[n][c].v, lacc[n], 0, 0, 0);
            #pragma unroll
            for (int t = 0; t < 4; ++t) {
                bf16x8 af = *(const bf16x8*)(cV + (t * 16 + l15) * 64 + pc * 8);
                #pragma unroll
                for (int n = 0; n < 2; ++n)
                    acco[n][t] = __builtin_amdgcn_mfma_f32_16x16x32_bf16(af, pb[n][c].v, acco[n][t], 0, 0, 0);
            }
        }
        __builtin_amdgcn_s_setprio(0);
        __syncthreads();   // drain prefetch (after compute) + free cur buffer
    }

    // ctx[B,S,DM]: row q = q0 + n*16 + l15, col = h*64 + t*16 + quad*4 (x4)
    #pragma unroll
    for (int n = 0; n < 2; ++n) {
        const float inv = 1.0f / lacc[n][0];   // all components equal
        bf16* crow = ctx + ((size_t)(b * SS + q0 + n * 16 + l15)) * DM + h * HD;
        #pragma unroll
        for (int t = 0; t < 4; ++t) {
            bf16x4 ov = { (bf16)(acco[n][t][0] * inv), (bf16)(acco[n][t][1] * inv),
                          (bf16)(acco[n][t][2] * inv), (bf16)(acco[n][t][3] * inv) };
            *(bf16x4*)(crow + t * 16 + quad * 4) = ov;
        }
    }
}

// ---------------------------------------------------------------------------
// Kernel 3: output projection + bias + residual x(fp32) -> h (bf16).
// 1-D grid of 768 (64 tileM x 12 tileN), XCD swizzle tileM = u % 64.
// ---------------------------------------------------------------------------
__global__ __launch_bounds__(256) void oproj_kernel(
    const bf16* __restrict__ ctx, const bf16* __restrict__ Wob,
    const float* __restrict__ bo, const float* __restrict__ x,
    bf16* __restrict__ hbuf)
{
    __shared__ __align__(16) bf16 As[2 * 128 * 32];
    __shared__ __align__(16) bf16 Bs[2 * 64 * 32];
    const int u = blockIdx.x;
    const int tileM = u & 63;
    const int tileN = u >> 6;           // 0..11

    floatx4 acc[2][4];
    #pragma unroll
    for (int i = 0; i < 2; ++i)
        #pragma unroll
        for (int j = 0; j < 4; ++j) { floatx4 zv = {0.f, 0.f, 0.f, 0.f}; acc[i][j] = zv; }

    gemm_mainloop64<1>(ctx, Wob, tileM, tileN, As, Bs, acc);

    const int lane = threadIdx.x & 63, wave = threadIdx.x >> 6;
    const int l15 = lane & 15, quad = lane >> 4;
    #pragma unroll
    for (int i = 0; i < 2; ++i) {
        const int sg = tileM * 128 + wave * 32 + i * 16 + l15;
        #pragma unroll
        for (int j = 0; j < 4; ++j) {
            const int o0 = tileN * 64 + j * 16 + quad * 4;
            float4 b4 = *(const float4*)(bo + o0);
            float4 r4 = *(const float4*)(x + (size_t)sg * DM + o0);
            bf16x4 pk = { (bf16)(acc[i][j][0] + b4.x + r4.x),
                          (bf16)(acc[i][j][1] + b4.y + r4.y),
                          (bf16)(acc[i][j][2] + b4.z + r4.z),
                          (bf16)(acc[i][j][3] + b4.w + r4.w) };
            *(bf16x4*)(hbuf + (size_t)sg * DM + o0) = pk;
        }
    }
}

// ---------------------------------------------------------------------------
// Kernel 4: LayerNorm, one wave per row (768 elems = 12/lane), eps=1e-12.
// ---------------------------------------------------------------------------
__global__ __launch_bounds__(256) void ln_kernel(
    const bf16* __restrict__ hbuf, const float* __restrict__ g,
    const float* __restrict__ be, float* __restrict__ out)
{
    const int row  = blockIdx.x * 4 + (threadIdx.x >> 6);
    const int lane = threadIdx.x & 63;
    const bf16* hr = hbuf + (size_t)row * DM;

    bf16x8 va = *(const bf16x8*)(hr + lane * 8);          // elems [0,512)
    bf16x4 vb = *(const bf16x4*)(hr + 512 + lane * 4);    // elems [512,768)
    float v[12];
    #pragma unroll
    for (int i = 0; i < 8; ++i) v[i] = (float)va[i];
    #pragma unroll
    for (int i = 0; i < 4; ++i) v[8 + i] = (float)vb[i];

    float s = 0.f;
    #pragma unroll
    for (int i = 0; i < 12; ++i) s += v[i];
    #pragma unroll
    for (int m = 1; m < 64; m <<= 1) s += __shfl_xor(s, m);
    const float mu = s * (1.0f / DM);

    float s2 = 0.f;
    #pragma unroll
    for (int i = 0; i < 12; ++i) { v[i] -= mu; s2 += v[i] * v[i]; }
    #pragma unroll
    for (int m = 1; m < 64; m <<= 1) s2 += __shfl_xor(s2, m);
    const float rsv = rsqrtf(s2 * (1.0f / DM) + 1e-12f);

    float* orow = out + (size_t)row * DM;
    const int c0 = lane * 8, c1 = 512 + lane * 4;
    float4 g0 = *(const float4*)(g + c0),     g1 = *(const float4*)(g + c0 + 4);
    float4 g2 = *(const float4*)(g + c1);
    float4 b0 = *(const float4*)(be + c0),    b1 = *(const float4*)(be + c0 + 4);
    float4 b2 = *(const float4*)(be + c1);
    float4 o0 = { v[0]*rsv*g0.x + b0.x, v[1]*rsv*g0.y + b0.y,
                  v[2]*rsv*g0.z + b0.z, v[3]*rsv*g0.w + b0.w };
    float4 o1 = { v[4]*rsv*g1.x + b1.x, v[5]*rsv*g1.y + b1.y,
                  v[6]*rsv*g1.z + b1.z, v[7]*rsv*g1.w + b1.w };
    float4 o2 = { v[8]*rsv*g2.x + b2.x, v[9]*rsv*g2.y + b2.y,
                  v[10]*rsv*g2.z + b2.z, v[11]*rsv*g2.w + b2.w };
    *(float4*)(orow + c0)     = o0;
    *(float4*)(orow + c0 + 4) = o1;
    *(float4*)(orow + c1)     = o2;
}

// ---------------------------------------------------------------------------
extern "C" void kernel_launch(void* const* d_in, const int* in_sizes, int n_in,
                              void* d_out, int out_size, void* d_ws, size_t ws_size,
                              hipStream_t stream)
{
    const float* x    = (const float*)d_in[0];
    const float* mask = (const float*)d_in[1];
    const float* akey = (const float*)d_in[2];
    const float* aval = (const float*)d_in[3];
    const float* Wq = (const float*)d_in[4];  const float* bq = (const float*)d_in[5];
    const float* Wk = (const float*)d_in[6];  const float* bk = (const float*)d_in[7];
    const float* Wv = (const float*)d_in[8];  const float* bv = (const float*)d_in[9];
    const float* Wo = (const float*)d_in[10]; const float* bo = (const float*)d_in[11];
    const float* lng = (const float*)d_in[12]; const float* lnb = (const float*)d_in[13];
    float* outp = (float*)d_out;

    const size_t nqkv = (size_t)BB * HH * SS * HD;   // 6,291,456 elems
    char* ws = (char*)d_ws;
    bf16*  xb   = (bf16*)ws;   ws += N_X  * sizeof(bf16);
    bf16*  Wqb  = (bf16*)ws;   ws += N_W  * sizeof(bf16);
    bf16*  Wkb  = (bf16*)ws;   ws += N_W  * sizeof(bf16);
    bf16*  Wvb  = (bf16*)ws;   ws += N_W  * sizeof(bf16);
    bf16*  Wob  = (bf16*)ws;   ws += N_W  * sizeof(bf16);
    float* ml2e = (float*)ws;  ws += N_M  * sizeof(float);
    bf16*  qbuf = (bf16*)ws;   ws += nqkv * sizeof(bf16);
    bf16*  kbuf = (bf16*)ws;   ws += nqkv * sizeof(bf16);
    bf16*  vtbuf= (bf16*)ws;   ws += nqkv * sizeof(bf16);
    bf16*  ctxb = (bf16*)ws;   ws += nqkv * sizeof(bf16);
    bf16*  hbuf = (bf16*)ws;   ws += nqkv * sizeof(bf16);
    // total ~80 MB of d_ws

    const size_t ncvt = (N_X + 4 * N_W + N_M) / 4;       // threads, 4 elems each
    const int cvt_blocks = (int)((ncvt + 255) / 256);
    cvt_kernel<<<cvt_blocks, 256, 0, stream>>>(x, Wq, Wk, Wv, Wo, mask,
                                               xb, Wqb, Wkb, Wvb, Wob, ml2e);

    qkv_kernel<<<2304, 256, 0, stream>>>(xb, Wqb, bq, Wkb, bk, Wvb, bv, akey, aval,
                                         qbuf, kbuf, vtbuf);
    attn_kernel<<<768, 256, 0, stream>>>(qbuf, kbuf, vtbuf, ml2e, ctxb);
    oproj_kernel<<<768, 256, 0, stream>>>(ctxb, Wob, bo, x, hbuf);
    ln_kernel<<<MM / 4, 256, 0, stream>>>(hbuf, lng, lnb, outp);
}